// Round 3
// baseline (900.113 us; speedup 1.0000x reference)
//
#include <hip/hip_runtime.h>
#include <cstdint>

// Problem constants
#define M_TOK 32768   // B*S
#define BERT  768
#define HID   512
#define LAT   128
#define NV    4096
#define NK    100
#define VOCAB 30522
#define NB    128     // batch B

typedef short short8 __attribute__((ext_vector_type(8)));
typedef float floatx4 __attribute__((ext_vector_type(4)));
typedef unsigned short u16x4 __attribute__((ext_vector_type(4)));

// ---- bf16 split helpers (RNE, manual bit ops: no API ambiguity) -----------
__device__ __forceinline__ unsigned short f2bf(float f) {
    unsigned u = __float_as_uint(f);
    unsigned r = (u + 0x7FFFu + ((u >> 16) & 1u)) >> 16;
    return (unsigned short)r;
}
__device__ __forceinline__ float bf2f(unsigned short h) {
    return __uint_as_float((unsigned)h << 16);
}

// ---- async global->LDS, 16B per lane --------------------------------------
__device__ __forceinline__ void async16(const void* g, void* l) {
    __builtin_amdgcn_global_load_lds(
        (const __attribute__((address_space(1))) unsigned int*)g,
        (__attribute__((address_space(3))) unsigned int*)l, 16, 0, 0);
}

// ---------------------------------------------------------------------------
// Weight split+transpose: W[K][N] f32 -> Wt limbs [NL=3][N][K] bf16.
// ---------------------------------------------------------------------------
__global__ __launch_bounds__(256) void wsplit(
    const float* __restrict__ W, unsigned short* __restrict__ Wt,
    int K, int N)
{
    int j = blockIdx.x * 256 + threadIdx.x;     // index over [N][K]
    int total = N * K;
    if (j >= total) return;
    int n = j / K, k = j - n * K;
    float v = W[(size_t)k * N + n];
    unsigned short h = f2bf(v);
    float r = v - bf2f(h);
    unsigned short m = f2bf(r);
    float r2 = r - bf2f(m);
    unsigned short l = f2bf(r2);
    Wt[j] = h;
    Wt[(size_t)total + j] = m;
    Wt[(size_t)2 * total + j] = l;
}

// ---------------------------------------------------------------------------
// A-presplit: A[M][K] f32 -> planes [3][M][K] bf16 (same RNE chain as the
// in-kernel split it replaces -> bit-identical limbs). BW-bound.
// ---------------------------------------------------------------------------
__global__ __launch_bounds__(256) void asplit(
    const float* __restrict__ A, unsigned short* __restrict__ P, int total)
{
    int j = (blockIdx.x * 256 + threadIdx.x) * 4;
    if (j >= total) return;
    float4 v4 = *(const float4*)(A + j);
    float vv[4] = {v4.x, v4.y, v4.z, v4.w};
    u16x4 h4, m4, l4;
#pragma unroll
    for (int e = 0; e < 4; ++e) {
        float v = vv[e];
        unsigned short h = f2bf(v);
        float r = v - bf2f(h);
        unsigned short m = f2bf(r);
        float r2 = r - bf2f(m);
        h4[e] = h; m4[e] = m; l4[e] = f2bf(r2);
    }
    *(u16x4*)(P + j) = h4;
    *(u16x4*)(P + (size_t)total + j) = m4;
    *(u16x4*)(P + (size_t)2 * total + j) = l4;
}

// ---------------------------------------------------------------------------
// Multi-limb bf16 MFMA GEMM, legacy 128x128 structure (kept for enc2/dec1).
// OUT=0: f32 C (+bias, opt ReLU). OUT=2: write 2 bf16 limb planes of the
// post-bias/relu value into C (cast) -- feeds gemm_br's A operand.
// ---------------------------------------------------------------------------
template<int NL, bool RELU, int OUT = 0>
__global__ __launch_bounds__(256) void gemm_mfma(
    const float* __restrict__ A, const unsigned short* __restrict__ Wt,
    const float* __restrict__ bias, float* __restrict__ C,
    int M, int N, int K)
{
    __shared__ unsigned short Ash[NL][128 * 32];
    __shared__ unsigned short Bsh[NL][128 * 32];

    const int tid  = threadIdx.x;
    const int lane = tid & 63;
    const int wave = tid >> 6;
    const int bm = blockIdx.y * 128;
    const int bn = blockIdx.x * 128;
    const int wm = (wave & 1) * 64;
    const int wn = (wave >> 1) * 64;

    const int ar = tid >> 3;          // 0..31
    const int ak = (tid & 7) * 4;     // 0,4,..28
    const int br = tid >> 2;          // 0..63
    const int bk = (tid & 3) * 8;     // 0,8,16,24

    floatx4 acc[4][4];
#pragma unroll
    for (int t = 0; t < 4; ++t)
#pragma unroll
        for (int u = 0; u < 4; ++u)
            acc[t][u] = (floatx4)0.0f;

    float4 av[4];
#pragma unroll
    for (int i = 0; i < 4; ++i)
        av[i] = *(const float4*)(A + (size_t)(bm + ar + 32 * i) * K + ak);

    for (int k0 = 0; k0 < K; k0 += 32) {
        u16x4 ah[NL][4];
#pragma unroll
        for (int i = 0; i < 4; ++i) {
            float vv[4] = {av[i].x, av[i].y, av[i].z, av[i].w};
#pragma unroll
            for (int e = 0; e < 4; ++e) {
                float v = vv[e];
                unsigned short h = f2bf(v);
                float r = v - bf2f(h);
                unsigned short m = f2bf(r);
                ah[0][i][e] = h;
                ah[1][i][e] = m;
                if (NL == 3) {
                    float r2 = r - bf2f(m);
                    ah[2][i][e] = f2bf(r2);
                }
            }
        }
        __syncthreads();
#pragma unroll
        for (int l = 0; l < NL; ++l) {
            const unsigned short* wp = Wt + (size_t)l * N * K;
#pragma unroll
            for (int i = 0; i < 2; ++i)
                async16(wp + (size_t)(bn + br + 64 * i) * K + k0 + bk,
                        &Bsh[l][i * 2048 + tid * 8]);
        }
#pragma unroll
        for (int l = 0; l < NL; ++l)
#pragma unroll
            for (int i = 0; i < 4; ++i)
                *(u16x4*)&Ash[l][(ar + 32 * i) * 32 + ak] = ah[l][i];
        if (k0 + 32 < K) {
#pragma unroll
            for (int i = 0; i < 4; ++i)
                av[i] = *(const float4*)(A + (size_t)(bm + ar + 32 * i) * K + k0 + 32 + ak);
        }
        __syncthreads();

        short8 af[NL][4];
#pragma unroll
        for (int l = 0; l < NL; ++l)
#pragma unroll
            for (int t = 0; t < 4; ++t)
                af[l][t] = *(const short8*)&Ash[l][(wm + t * 16 + (lane & 15)) * 32 + (lane >> 4) * 8];

#pragma unroll
        for (int bl = 0; bl < NL; ++bl) {
            short8 bf[4];
#pragma unroll
            for (int u = 0; u < 4; ++u)
                bf[u] = *(const short8*)&Bsh[bl][(wn + u * 16 + (lane & 15)) * 32 + (lane >> 4) * 8];
#pragma unroll
            for (int al = 0; al < NL; ++al) {
                if (al + bl >= NL) continue;
#pragma unroll
                for (int t = 0; t < 4; ++t)
#pragma unroll
                    for (int u = 0; u < 4; ++u)
                        acc[t][u] = __builtin_amdgcn_mfma_f32_16x16x32_bf16(
                            af[al][t], bf[u], acc[t][u], 0, 0, 0);
            }
        }
    }

    unsigned short* P0 = (unsigned short*)C;
    unsigned short* P1 = P0 + (size_t)M * N;
#pragma unroll
    for (int t = 0; t < 4; ++t) {
        int row0 = bm + wm + t * 16 + (lane >> 4) * 4;
#pragma unroll
        for (int u = 0; u < 4; ++u) {
            int col = bn + wn + u * 16 + (lane & 15);
            float b = bias[col];
#pragma unroll
            for (int r = 0; r < 4; ++r) {
                float v = acc[t][u][r] + b;
                if (RELU) v = fmaxf(v, 0.f);
                if (OUT == 0) {
                    C[(size_t)(row0 + r) * N + col] = v;
                } else {
                    unsigned short hh = f2bf(v);
                    unsigned short mm = f2bf(v - bf2f(hh));
                    P0[(size_t)(row0 + r) * N + col] = hh;
                    P1[(size_t)(row0 + r) * N + col] = mm;
                }
            }
        }
    }
}

// ---------------------------------------------------------------------------
// 256x256 / BK=64 multi-limb GEMM, B-in-registers variant.
// Theory (r2 post-mortem): per-phase lgkmcnt(0)+barrier lockstep serializes
// the LDS pipe (2300cyc/tile) against MFMA (2480cyc/tile). Fix:
//  - B (<=2.4MB, L2-resident) is NOT staged in LDS: each wave global-loads
//    its 8 B-frags to regs each tile; gated by counted vmcnt(4) (stage loads
//    stay in flight). Kills 1/3 of LDS reads + all B staging.
//  - Only A staged (swizzled, conflict-free verified r1/r2); 16 ds_reads/
//    wave/tile gated by counted lgkmcnt(4)/(0); a-hi read after Q1 reusing
//    the a-lo registers (VGPR-safe), service overlaps via wave skew.
//  - ONE s_barrier per K-tile -> waves desynchronize, pipes overlap.
// Chunk order / fragment layout / epilogue identical to r1/r2 (absmax
// canary 0.0009765625 must hold).
// XCD pairing: blocks sharing A-rows (same by, all bx) mapped to the same
// XCD assuming dispatch XCD = linear_id % 8 (perf-only heuristic).
// ---------------------------------------------------------------------------
template<int NP, bool RELU>
__global__ __launch_bounds__(512, 2) void gemm_br(
    const unsigned short* __restrict__ Ap,   // [NLA][M][K] bf16 planes
    const unsigned short* __restrict__ Bp,   // [NLB][N][K] bf16 planes
    const float* __restrict__ bias, float* __restrict__ C,
    int M, int N, int K, int NT)             // NT = NP*K/64 (>= 2)
{
    __shared__ unsigned short As[2][256 * 64];   // 2 x 32 KiB

    const int tid  = threadIdx.x;
    const int lane = tid & 63;
    const int wid  = tid >> 6;
    const int wm   = (wid & 1) * 128;
    const int wn   = (wid >> 1) * 64;

    // XCD pairing remap: ids {k, k+8, k+16, ...} share an XCD (id%8 model).
    // bx' = (id/8)%gx, by' = (id%8) + 8*(id/(8*gx)); bijective for gy%8==0.
    const int gx = gridDim.x;
    const int id = blockIdx.x + gx * blockIdx.y;
    const int bxp = (id >> 3) % gx;
    const int byp = (id & 7) + 8 * (id / (8 * gx));
    const int bm  = byp * 256;
    const int bn  = bxp * 256;

    // swizzled LDS read constants (row&7 == lane&7 for fragment rows)
    const int laneR = lane & 15;
    const int kgrp  = lane >> 4;
    const int swz   = lane & 7;
    const int slot0 = ((kgrp)     ^ swz) * 8;
    const int slot1 = ((4 + kgrp) ^ swz) * 8;
    const int abase = (wm + laneR) * 64;

    // per-lane B element offsets (invariant): row*K + kgrp*8, 32-bit
    unsigned rowOff[4];
#pragma unroll
    for (int nf = 0; nf < 4; ++nf)
        rowOff[nf] = (unsigned)(bn + wn + nf * 16 + laneR) * (unsigned)K
                   + (unsigned)(kgrp * 8);

    floatx4 acc[8][4];
#pragma unroll
    for (int m = 0; m < 8; ++m)
#pragma unroll
        for (int n = 0; n < 4; ++n) acc[m][n] = (floatx4)0.0f;

    // chunk decode: c -> (ki, al, bl); order == legacy limb-product order
    auto decode = [&](int c, int& ki, int& al, int& bl) {
        if (NP == 6) {
            ki = c / 6; int j = c - ki * 6;
            al = j < 3 ? j : (j < 5 ? j - 3 : 0);
            bl = j < 3 ? 0 : (j < 5 ? 1 : 2);
        } else {
            ki = c / 3; int j = c - ki * 3;
            al = (j == 1); bl = (j == 2);
        }
    };

    // stage full A k'-tile (4 x global_load_lds, inverse-swizzled source)
    auto stageA = [&](int T) {
        int ki0, al0, bl0, ki1, al1, bl1;
        decode(2 * T, ki0, al0, bl0);
        decode(2 * T + 1, ki1, al1, bl1);
        const unsigned short* A0 = Ap + (size_t)al0 * M * K + (size_t)ki0 * 32;
        const unsigned short* A1 = Ap + (size_t)al1 * M * K + (size_t)ki1 * 32;
        unsigned short* dst = &As[T & 1][0];
#pragma unroll
        for (int i = 0; i < 4; ++i) {
            int s   = i * 512 + tid;
            int row = s >> 3;
            int e0  = ((s & 7) ^ (row & 7)) * 8;
            const unsigned short* src = ((e0 & 32) ? A1 : A0)
                                        + (size_t)(bm + row) * K + (e0 & 31);
            async16(src, dst + row * 64 + (tid & 7) * 8);
        }
    };

    // prologue
    stageA(0);
    asm volatile("s_waitcnt vmcnt(0)" ::: "memory");
    __builtin_amdgcn_s_barrier();

    for (int t = 0; t < NT; ++t) {
        const int cb = t & 1;
        const unsigned short* Ab = &As[cb][0];
        short8 af[4][2], b[4][2];

        // --- A-lo ds reads, pinned in m-pairs for counted lgkm gates ---
        af[0][0] = *(const short8*)&Ab[abase + 0 * 1024 + slot0];
        af[0][1] = *(const short8*)&Ab[abase + 0 * 1024 + slot1];
        af[1][0] = *(const short8*)&Ab[abase + 1 * 1024 + slot0];
        af[1][1] = *(const short8*)&Ab[abase + 1 * 1024 + slot1];
        __builtin_amdgcn_sched_barrier(0);
        af[2][0] = *(const short8*)&Ab[abase + 2 * 1024 + slot0];
        af[2][1] = *(const short8*)&Ab[abase + 2 * 1024 + slot1];
        af[3][0] = *(const short8*)&Ab[abase + 3 * 1024 + slot0];
        af[3][1] = *(const short8*)&Ab[abase + 3 * 1024 + slot1];
        __builtin_amdgcn_sched_barrier(0);

        // --- B direct global->reg (8 x dwordx4), then stage A(t+1) ---
        int ki0, al0, bl0, ki1, al1, bl1;
        decode(2 * t, ki0, al0, bl0);
        decode(2 * t + 1, ki1, al1, bl1);
        const unsigned short* B0 = Bp + (size_t)bl0 * N * K + (size_t)ki0 * 32;
        const unsigned short* B1 = Bp + (size_t)bl1 * N * K + (size_t)ki1 * 32;
#pragma unroll
        for (int nf = 0; nf < 4; ++nf) {
            b[nf][0] = *(const short8*)(B0 + rowOff[nf]);
            b[nf][1] = *(const short8*)(B1 + rowOff[nf]);
        }
        __builtin_amdgcn_sched_barrier(0);
        if (t + 1 < NT) stageA(t + 1);
        __builtin_amdgcn_sched_barrier(0);

        // --- Q0a: m=0,1 x n=0,1 (needs first 4 ds reads + all B) ---
        asm volatile("s_waitcnt lgkmcnt(4)" ::: "memory");
        if (t + 1 < NT) asm volatile("s_waitcnt vmcnt(4)" ::: "memory");
        else            asm volatile("s_waitcnt vmcnt(0)" ::: "memory");
        __builtin_amdgcn_sched_barrier(0);
        __builtin_amdgcn_s_setprio(1);
#pragma unroll
        for (int m = 0; m < 2; ++m)
#pragma unroll
            for (int n = 0; n < 2; ++n)
#pragma unroll
                for (int kk = 0; kk < 2; ++kk)
                    acc[m][n] = __builtin_amdgcn_mfma_f32_16x16x32_bf16(
                        af[m][kk], b[n][kk], acc[m][n], 0, 0, 0);
        __builtin_amdgcn_s_setprio(0);

        // --- Q0b: m=2,3 x n=0,1 ; Q1: m=0..3 x n=2,3 ---
        asm volatile("s_waitcnt lgkmcnt(0)" ::: "memory");
        __builtin_amdgcn_sched_barrier(0);
        __builtin_amdgcn_s_setprio(1);
#pragma unroll
        for (int m = 2; m < 4; ++m)
#pragma unroll
            for (int n = 0; n < 2; ++n)
#pragma unroll
                for (int kk = 0; kk < 2; ++kk)
                    acc[m][n] = __builtin_amdgcn_mfma_f32_16x16x32_bf16(
                        af[m][kk], b[n][kk], acc[m][n], 0, 0, 0);
#pragma unroll
        for (int m = 0; m < 4; ++m)
#pragma unroll
            for (int n = 0; n < 2; ++n)
#pragma unroll
                for (int kk = 0; kk < 2; ++kk)
                    acc[m][2 + n] = __builtin_amdgcn_mfma_f32_16x16x32_bf16(
                        af[m][kk], b[2 + n][kk], acc[m][2 + n], 0, 0, 0);
        __builtin_amdgcn_s_setprio(0);
        __builtin_amdgcn_sched_barrier(0);

        // --- A-hi ds reads into same regs (a-lo dead after Q1) ---
        af[0][0] = *(const short8*)&Ab[abase + 4 * 1024 + slot0];
        af[0][1] = *(const short8*)&Ab[abase + 4 * 1024 + slot1];
        af[1][0] = *(const short8*)&Ab[abase + 5 * 1024 + slot0];
        af[1][1] = *(const short8*)&Ab[abase + 5 * 1024 + slot1];
        af[2][0] = *(const short8*)&Ab[abase + 6 * 1024 + slot0];
        af[2][1] = *(const short8*)&Ab[abase + 6 * 1024 + slot1];
        af[3][0] = *(const short8*)&Ab[abase + 7 * 1024 + slot0];
        af[3][1] = *(const short8*)&Ab[abase + 7 * 1024 + slot1];
        asm volatile("s_waitcnt lgkmcnt(0)" ::: "memory");
        __builtin_amdgcn_sched_barrier(0);
        __builtin_amdgcn_s_setprio(1);
        // --- Q2: m-hi x n-hi ; Q3: m-hi x n-lo ---
#pragma unroll
        for (int m = 0; m < 4; ++m)
#pragma unroll
            for (int n = 0; n < 2; ++n)
#pragma unroll
                for (int kk = 0; kk < 2; ++kk)
                    acc[4 + m][2 + n] = __builtin_amdgcn_mfma_f32_16x16x32_bf16(
                        af[m][kk], b[2 + n][kk], acc[4 + m][2 + n], 0, 0, 0);
#pragma unroll
        for (int m = 0; m < 4; ++m)
#pragma unroll
            for (int n = 0; n < 2; ++n)
#pragma unroll
                for (int kk = 0; kk < 2; ++kk)
                    acc[4 + m][n] = __builtin_amdgcn_mfma_f32_16x16x32_bf16(
                        af[m][kk], b[n][kk], acc[4 + m][n], 0, 0, 0);
        __builtin_amdgcn_s_setprio(0);

        // tile boundary: stage(t+1) complete, then barrier
        asm volatile("s_waitcnt vmcnt(0)" ::: "memory");
        __builtin_amdgcn_s_barrier();
    }

    // epilogue: D col=lane&15, row=(lane>>4)*4+reg  [m89/m91-verified]
#pragma unroll
    for (int mf = 0; mf < 8; ++mf) {
        int row0 = bm + wm + mf * 16 + (lane >> 4) * 4;
#pragma unroll
        for (int nf = 0; nf < 4; ++nf) {
            int col = bn + wn + nf * 16 + (lane & 15);
            float bb = bias[col];
#pragma unroll
            for (int r = 0; r < 4; ++r) {
                float v = acc[mf][nf][r] + bb;
                if (RELU) v = fmaxf(v, 0.f);
                C[(size_t)(row0 + r) * N + col] = v;
            }
        }
    }
}

// ---------------------------------------------------------------------------
// Row L2-normalize, rows of length 128. One wave (64 lanes) per row.
// ---------------------------------------------------------------------------
__global__ __launch_bounds__(64) void rownorm128(const float* __restrict__ in,
                                                 float* __restrict__ out)
{
    int row = blockIdx.x;
    int l = threadIdx.x;
    const float* p = in + (size_t)row * 128;
    float v0 = p[l], v1 = p[l + 64];
    float s = v0 * v0 + v1 * v1;
#pragma unroll
    for (int o = 32; o > 0; o >>= 1) s += __shfl_xor(s, o, 64);
    float inv = 1.0f / sqrtf(s);
    float* q = out + (size_t)row * 128;
    q[l] = v0 * inv;
    q[l + 64] = v1 * inv;
}

// ---------------------------------------------------------------------------
__global__ __launch_bounds__(128) void seg_scatter(
    const float* __restrict__ z, const int* __restrict__ ids,
    float* __restrict__ seg, float* __restrict__ freq)
{
    int row = blockIdx.x;
    int l = threadIdx.x;
    int id = ids[row];
    atomicAdd(&seg[(size_t)id * 128 + l], z[(size_t)row * 128 + l]);
    if (l == 0) atomicAdd(&freq[id], 1.0f);
}

// ---------------------------------------------------------------------------
__global__ __launch_bounds__(128) void avg_kernel(
    const float* __restrict__ seg, const float* __restrict__ freq,
    float* __restrict__ avg)
{
    int i = blockIdx.x;
    int l = threadIdx.x;
    float f = fmaxf(freq[i], 1.0f);
    avg[(size_t)i * 128 + l] = seg[(size_t)i * 128 + l] / f;
}

// ---------------------------------------------------------------------------
__global__ __launch_bounds__(128) void argmax_kernel(
    const float* __restrict__ avg, const float* __restrict__ cn,
    int* __restrict__ cids, float* __restrict__ cids_f)
{
    __shared__ float arow[128];
    __shared__ float lg[NK];
    int row = blockIdx.x;
    int t = threadIdx.x;
    arow[t] = avg[(size_t)row * 128 + t];
    __syncthreads();
    if (t < NK) {
        float d = 0.f;
        const float* c = cn + (size_t)t * 128;
#pragma unroll 8
        for (int i = 0; i < 128; ++i) d += arow[i] * c[i];
        lg[t] = d;
    }
    __syncthreads();
    if (t == 0) {
        float best = lg[0];
        int bi = 0;
        for (int k = 1; k < NK; ++k) {
            if (lg[k] > best) { best = lg[k]; bi = k; }
        }
        cids[row] = bi;
        cids_f[row] = (float)bi;
    }
}

// ---------------------------------------------------------------------------
__global__ __launch_bounds__(256) void build_masks(
    const float* __restrict__ bow, unsigned long long* __restrict__ masks,
    float* __restrict__ cnt)
{
    int j = blockIdx.x * 256 + threadIdx.x;
    if (j >= NV) return;
    unsigned long long m0 = 0, m1 = 0;
    for (int b = 0; b < 64; ++b)
        if (bow[(size_t)b * VOCAB + j] != 0.f) m0 |= 1ull << b;
    for (int b = 0; b < 64; ++b)
        if (bow[(size_t)(b + 64) * VOCAB + j] != 0.f) m1 |= 1ull << b;
    masks[2 * j] = m0;
    masks[2 * j + 1] = m1;
    cnt[j] = (float)(__popcll(m0) + __popcll(m1));
}

// ---------------------------------------------------------------------------
__global__ __launch_bounds__(256) void co_kernel(
    const unsigned long long* __restrict__ masks, const float* __restrict__ cnt,
    float* __restrict__ co)
{
    int j = blockIdx.x * 256 + threadIdx.x;
    unsigned long long m0 = masks[2 * j], m1 = masks[2 * j + 1];
    float cj = cnt[j];
    int ibase = blockIdx.y * 64;
    for (int ii = 0; ii < 64; ++ii) {
        int i = ibase + ii;
        unsigned long long a0 = masks[2 * i], a1 = masks[2 * i + 1];
        float ci = cnt[i];
        float c = (float)(__popcll(a0 & m0) + __popcll(a1 & m1));
        co[(size_t)i * NV + j] = (float)NB * c / (ci * cj);
    }
}

// ---------------------------------------------------------------------------
__global__ __launch_bounds__(128) void cluster_scan(
    const float* __restrict__ avg, const int* __restrict__ cids,
    const float* __restrict__ freq, const float* __restrict__ vw,
    const float* __restrict__ centers, const float* __restrict__ counts,
    float* __restrict__ out_centers)
{
    __shared__ int list[NV];
    __shared__ float coef[NV];
    __shared__ int tcnt[128];
    __shared__ int tot;
    __shared__ float Ptot;

    int k = blockIdx.x;
    int t = threadIdx.x;

    int base = t * (NV / 128);
    int c = 0;
    for (int s = 0; s < NV / 128; ++s) {
        int i = base + s;
        if (cids[i] == k && freq[i] > 0.f) c++;
    }
    tcnt[t] = c;
    __syncthreads();
    if (t == 0) {
        int run = 0;
        for (int x = 0; x < 128; ++x) { int v = tcnt[x]; tcnt[x] = run; run += v; }
        tot = run;
    }
    __syncthreads();
    int off = tcnt[t];
    for (int s = 0; s < NV / 128; ++s) {
        int i = base + s;
        if (cids[i] == k && freq[i] > 0.f) list[off++] = i;
    }
    __syncthreads();
    int m = tot;

    float c0 = counts[k];
    for (int j = t; j < m; j += 128)
        coef[j] = vw[list[j]] / (c0 + (float)(j + 1));
    __syncthreads();
    if (t == 0) {
        float suf = 1.f;
        for (int j = m - 1; j >= 0; --j) {
            float e = coef[j];
            coef[j] = e * suf;
            suf *= (1.f - e);
        }
        Ptot = suf;
    }
    __syncthreads();

    float accv = Ptot * centers[(size_t)k * 128 + t];
    for (int j = 0; j < m; ++j)
        accv += coef[j] * avg[(size_t)list[j] * 128 + t];
    out_centers[(size_t)k * 128 + t] = accv;
}

// ---------------------------------------------------------------------------
__global__ __launch_bounds__(64) void cn_norm(const float* __restrict__ centers,
                                              float* __restrict__ cn)
{
    int row = blockIdx.x;
    int l = threadIdx.x;
    const float* p = centers + (size_t)row * 128;
    float v0 = p[l], v1 = p[l + 64];
    float s = v0 * v0 + v1 * v1;
#pragma unroll
    for (int o = 32; o > 0; o >>= 1) s += __shfl_xor(s, o, 64);
    float inv = 1.0f / sqrtf(s);
    cn[(size_t)row * 128 + l] = v0 * inv;
    cn[(size_t)row * 128 + l + 64] = v1 * inv;
}

// ---------------------------------------------------------------------------
extern "C" void kernel_launch(void* const* d_in, const int* in_sizes, int n_in,
                              void* d_out, int out_size, void* d_ws, size_t ws_size,
                              hipStream_t stream)
{
    const int*   input_ids = (const int*)d_in[0];
    const float* token_embs = (const float*)d_in[3];
    const float* bow       = (const float*)d_in[4];
    const float* enc_w1    = (const float*)d_in[5];
    const float* enc_b1    = (const float*)d_in[6];
    const float* enc_w2    = (const float*)d_in[7];
    const float* enc_b2    = (const float*)d_in[8];
    const float* dec_w1    = (const float*)d_in[9];
    const float* dec_b1    = (const float*)d_in[10];
    const float* dec_w2    = (const float*)d_in[11];
    const float* dec_b2    = (const float*)d_in[12];
    const float* centers   = (const float*)d_in[13];
    const float* counts    = (const float*)d_in[14];
    const float* vocab_w   = (const float*)d_in[15];

    float* out = (float*)d_out;
    const size_t OFF_CO  = 0;                       // 4096*4096
    const size_t OFF_REC = 16777216;                // 32768*768
    const size_t OFF_AVG = OFF_REC + 25165824;      // 4096*128
    const size_t OFF_CID = OFF_AVG + 524288;        // 4096
    const size_t OFF_NC  = OFF_CID + 4096;          // 100*128

    // workspace layout
    float* h    = (float*)d_ws;                     // 32768*512 f32 (later: h2 limb planes)
    float* z    = h + (size_t)M_TOK * HID;          // 32768*128
    float* seg  = z + (size_t)M_TOK * LAT;          // 4096*128
    float* freq = seg + (size_t)NV * LAT;           // 4096
    float* cn   = freq + NV;                        // 100*128
    float* cntv = cn + (size_t)NK * LAT;            // 4096
    int*   cids = (int*)(cntv + NV);                // 4096
    unsigned long long* masks = (unsigned long long*)(cids + NV); // 4096*2
    unsigned short* wt1 = (unsigned short*)(masks + 2 * NV);      // 3*512*768
    unsigned short* wt2 = wt1 + (size_t)3 * HID * BERT;           // 3*128*512
    unsigned short* wt3 = wt2 + (size_t)3 * LAT * HID;            // 3*512*128
    unsigned short* wt4 = wt3 + (size_t)3 * HID * LAT;            // 3*768*512

    // token_embs limb planes (151 MB) live in the out-buffer's co+rec region
    // (167.8 MB). Consumed by enc1 BEFORE co_kernel/dec2 overwrite that
    // region later in the (serial) stream.
    unsigned short* a1p = (unsigned short*)out;

    // zero the atomic targets
    hipMemsetAsync(seg, 0, (size_t)(NV * LAT + NV) * sizeof(float), stream);

    // weight split+transpose (bf16 limbs, [N][K])
    wsplit<<<(BERT * HID + 255) / 256, 256, 0, stream>>>(enc_w1, wt1, BERT, HID);
    wsplit<<<(HID * LAT + 255) / 256, 256, 0, stream>>>(enc_w2, wt2, HID, LAT);
    wsplit<<<(LAT * HID + 255) / 256, 256, 0, stream>>>(dec_w1, wt3, LAT, HID);
    wsplit<<<(HID * BERT + 255) / 256, 256, 0, stream>>>(dec_w2, wt4, HID, BERT);

    // A-presplit for enc1 (bit-identical RNE limbs)
    asplit<<<(M_TOK * BERT / 4 + 255) / 256, 256, 0, stream>>>(
        token_embs, a1p, M_TOK * BERT);

    // encoder GEMM1: B-in-reg 256x256, K' = 6*768 = 4608 -> h f32 (RELU)
    gemm_br<6, true><<<dim3(HID / 256, M_TOK / 256), 512, 0, stream>>>(
        a1p, wt1, enc_b1, h, M_TOK, HID, BERT, 6 * BERT / 64);

    // encoder GEMM2 (legacy structure; grid.x=1 so no redundant split)
    gemm_mfma<3, false><<<dim3(LAT / 128, M_TOK / 128), 256, 0, stream>>>(
        h, wt2, enc_b2, z, M_TOK, LAT, HID);
    rownorm128<<<M_TOK, 64, 0, stream>>>(z, z);

    // decoder GEMM1 (legacy): writes h2 as 2 bf16 limb planes into h buffer
    gemm_mfma<2, true, 2><<<dim3(HID / 128, M_TOK / 128), 256, 0, stream>>>(
        z, wt3, dec_b1, h, M_TOK, HID, LAT);

    // decoder GEMM2: B-in-reg 256x256, K' = 3*512 = 1536 -> rec f32
    gemm_br<3, false><<<dim3(BERT / 256, M_TOK / 256), 512, 0, stream>>>(
        (const unsigned short*)h, wt4, dec_b2, out + OFF_REC,
        M_TOK, BERT, HID, 3 * HID / 64);

    // segment mean
    seg_scatter<<<M_TOK, 128, 0, stream>>>(z, input_ids, seg, freq);
    avg_kernel<<<NV, 128, 0, stream>>>(seg, freq, out + OFF_AVG);

    // cluster assignment
    cn_norm<<<NK, 64, 0, stream>>>(centers, cn);
    argmax_kernel<<<NV, 128, 0, stream>>>(out + OFF_AVG, cn, cids, out + OFF_CID);

    // co-occurrence matrix (overwrites a1p region -- after enc1, safe)
    build_masks<<<NV / 256, 256, 0, stream>>>(bow, masks, cntv);
    co_kernel<<<dim3(NV / 256, NV / 64), 256, 0, stream>>>(masks, cntv, out + OFF_CO);

    // online center update (closed form)
    cluster_scan<<<NK, 128, 0, stream>>>(out + OFF_AVG, cids, freq, vocab_w,
                                         centers, counts, out + OFF_NC);
}

// Round 6
// 675.416 us; speedup vs baseline: 1.3327x; 1.3327x over previous
//
#include <hip/hip_runtime.h>
#include <cstdint>

// Problem constants
#define M_TOK 32768   // B*S
#define BERT  768
#define HID   512
#define LAT   128
#define NV    4096
#define NK    100
#define VOCAB 30522
#define NB    128     // batch B

typedef short short8 __attribute__((ext_vector_type(8)));
typedef float floatx4 __attribute__((ext_vector_type(4)));
typedef int   intx4  __attribute__((ext_vector_type(4)));
typedef unsigned short u16x4 __attribute__((ext_vector_type(4)));

// ---- bf16 split helpers (RNE, manual bit ops) -----------------------------
__device__ __forceinline__ unsigned short f2bf(float f) {
    unsigned u = __float_as_uint(f);
    unsigned r = (u + 0x7FFFu + ((u >> 16) & 1u)) >> 16;
    return (unsigned short)r;
}
__device__ __forceinline__ float bf2f(unsigned short h) {
    return __uint_as_float((unsigned)h << 16);
}

// ---- async global->LDS, 16B per lane --------------------------------------
__device__ __forceinline__ void async16(const void* g, void* l) {
    __builtin_amdgcn_global_load_lds(
        (const __attribute__((address_space(1))) unsigned int*)g,
        (__attribute__((address_space(3))) unsigned int*)l, 16, 0, 0);
}

// ---------------------------------------------------------------------------
// Weight split+transpose: W[K][N] f32 -> Wt limbs [3][N][K] bf16.
// ---------------------------------------------------------------------------
__global__ __launch_bounds__(256) void wsplit(
    const float* __restrict__ W, unsigned short* __restrict__ Wt,
    int K, int N)
{
    int j = blockIdx.x * 256 + threadIdx.x;     // index over [N][K]
    int total = N * K;
    if (j >= total) return;
    int n = j / K, k = j - n * K;
    float v = W[(size_t)k * N + n];
    unsigned short h = f2bf(v);
    float r = v - bf2f(h);
    unsigned short m = f2bf(r);
    float r2 = r - bf2f(m);
    unsigned short l = f2bf(r2);
    Wt[j] = h;
    Wt[(size_t)total + j] = m;
    Wt[(size_t)2 * total + j] = l;
}

// ---------------------------------------------------------------------------
// Weight split+transpose to i8 fixed-point: W[K][N] f32 -> [2][N][K] i8.
// w_fix = rint(w*scale) = b0*256 + b1, b0,b1 in [-128,127].
// dec_w2 ~ N(0,0.02^2): |w|max ~ 0.1 -> fx < 2^15 at scale 2^18 (safe).
// ---------------------------------------------------------------------------
__global__ __launch_bounds__(256) void wsplit_i8(
    const float* __restrict__ W, signed char* __restrict__ Wt,
    int K, int N, float scale)
{
    int j = blockIdx.x * 256 + threadIdx.x;
    int total = N * K;
    if (j >= total) return;
    int n = j / K, k = j - n * K;
    float v = W[(size_t)k * N + n];
    int fx = (int)rintf(v * scale);
    fx = fx > 32639 ? 32639 : (fx < -32640 ? -32640 : fx);
    int b1 = ((fx + 128) & 255) - 128;
    int b0 = (fx - b1) >> 8;
    Wt[j] = (signed char)b0;
    Wt[(size_t)total + j] = (signed char)b1;
}

// ---------------------------------------------------------------------------
// Multi-limb bf16 MFMA GEMM, r0-verified 128x128 structure.
// OUT=0: f32 C (+bias, opt ReLU).
// OUT=1: write post-bias/relu value as i8 2-limb planes (scale 2^16) into C
//        -- feeds gemm_i8's A operand. h2 in [0,~0.23] (Cauchy-Schwarz on
//        unit-norm z, dec_w1 cols) => fx < 2^15, a0 <= ~77: safe.
// XCD remap (r3-verified FETCH cut): ids {k, k+8, ...} share an XCD
// (dispatch id%8 model); bijective for gridDim.y % 8 == 0. Numerics-neutral.
// ---------------------------------------------------------------------------
template<int NL, bool RELU, int OUT = 0>
__global__ __launch_bounds__(256) void gemm_mfma(
    const float* __restrict__ A, const unsigned short* __restrict__ Wt,
    const float* __restrict__ bias, float* __restrict__ C,
    int M, int N, int K)
{
    __shared__ unsigned short Ash[NL][128 * 32];
    __shared__ unsigned short Bsh[NL][128 * 32];

    const int tid  = threadIdx.x;
    const int lane = tid & 63;
    const int wave = tid >> 6;
    // XCD-aware bijective remap (identity when gridDim.x==1)
    const int gx  = gridDim.x;
    const int id  = blockIdx.x + gx * blockIdx.y;
    const int bxp = (id >> 3) % gx;
    const int byp = (id & 7) + 8 * (id / (8 * gx));
    const int bm  = byp * 128;
    const int bn  = bxp * 128;
    const int wm = (wave & 1) * 64;
    const int wn = (wave >> 1) * 64;

    const int ar = tid >> 3;          // 0..31
    const int ak = (tid & 7) * 4;     // 0,4,..28
    const int br = tid >> 2;          // 0..63
    const int bk = (tid & 3) * 8;     // 0,8,16,24

    floatx4 acc[4][4];
#pragma unroll
    for (int t = 0; t < 4; ++t)
#pragma unroll
        for (int u = 0; u < 4; ++u)
            acc[t][u] = (floatx4)0.0f;

    float4 av[4];
#pragma unroll
    for (int i = 0; i < 4; ++i)
        av[i] = *(const float4*)(A + (size_t)(bm + ar + 32 * i) * K + ak);

    for (int k0 = 0; k0 < K; k0 += 32) {
        u16x4 ah[NL][4];
#pragma unroll
        for (int i = 0; i < 4; ++i) {
            float vv[4] = {av[i].x, av[i].y, av[i].z, av[i].w};
#pragma unroll
            for (int e = 0; e < 4; ++e) {
                float v = vv[e];
                unsigned short h = f2bf(v);
                float r = v - bf2f(h);
                unsigned short m = f2bf(r);
                ah[0][i][e] = h;
                ah[1][i][e] = m;
                if constexpr (NL == 3) {
                    float r2 = r - bf2f(m);
                    ah[2][i][e] = f2bf(r2);
                }
            }
        }
        __syncthreads();
#pragma unroll
        for (int l = 0; l < NL; ++l) {
            const unsigned short* wp = Wt + (size_t)l * N * K;
#pragma unroll
            for (int i = 0; i < 2; ++i)
                async16(wp + (size_t)(bn + br + 64 * i) * K + k0 + bk,
                        &Bsh[l][i * 2048 + tid * 8]);
        }
#pragma unroll
        for (int l = 0; l < NL; ++l)
#pragma unroll
            for (int i = 0; i < 4; ++i)
                *(u16x4*)&Ash[l][(ar + 32 * i) * 32 + ak] = ah[l][i];
        if (k0 + 32 < K) {
#pragma unroll
            for (int i = 0; i < 4; ++i)
                av[i] = *(const float4*)(A + (size_t)(bm + ar + 32 * i) * K + k0 + 32 + ak);
        }
        __syncthreads();

        short8 af[NL][4];
#pragma unroll
        for (int l = 0; l < NL; ++l)
#pragma unroll
            for (int t = 0; t < 4; ++t)
                af[l][t] = *(const short8*)&Ash[l][(wm + t * 16 + (lane & 15)) * 32 + (lane >> 4) * 8];

#pragma unroll
        for (int bl = 0; bl < NL; ++bl) {
            short8 bf[4];
#pragma unroll
            for (int u = 0; u < 4; ++u)
                bf[u] = *(const short8*)&Bsh[bl][(wn + u * 16 + (lane & 15)) * 32 + (lane >> 4) * 8];
#pragma unroll
            for (int al = 0; al < NL; ++al) {
                if (al + bl >= NL) continue;
#pragma unroll
                for (int t = 0; t < 4; ++t)
#pragma unroll
                    for (int u = 0; u < 4; ++u)
                        acc[t][u] = __builtin_amdgcn_mfma_f32_16x16x32_bf16(
                            af[al][t], bf[u], acc[t][u], 0, 0, 0);
            }
        }
    }

    signed char* P0 = (signed char*)C;
    signed char* P1 = P0 + (size_t)M * N;
#pragma unroll
    for (int t = 0; t < 4; ++t) {
        int row0 = bm + wm + t * 16 + (lane >> 4) * 4;
#pragma unroll
        for (int u = 0; u < 4; ++u) {
            int col = bn + wn + u * 16 + (lane & 15);
            float b = bias[col];
#pragma unroll
            for (int r = 0; r < 4; ++r) {
                float v = acc[t][u][r] + b;
                if (RELU) v = fmaxf(v, 0.f);
                if constexpr (OUT == 0) {
                    C[(size_t)(row0 + r) * N + col] = v;
                } else {
                    int fx = (int)rintf(v * 65536.f);
                    fx = fx > 32639 ? 32639 : (fx < 0 ? 0 : fx);
                    int a1 = ((fx + 128) & 255) - 128;
                    int a0 = (fx - a1) >> 8;
                    P0[(size_t)(row0 + r) * N + col] = (signed char)a0;
                    P1[(size_t)(row0 + r) * N + col] = (signed char)a1;
                }
            }
        }
    }
}

// ---------------------------------------------------------------------------
// i8 fixed-point GEMM (dec2): C = A @ B^T * 2^-34 (+bias).
// A: [2][M][K] i8 limb planes (h2, scale 2^16); B: [2][N][K] i8 (w, 2^18).
// Products g = al+bl <= 1: (0,0)->acc0, (1,0)+(0,1)->acc1; dropped (1,1)
// term ~ 1e-5 RMS on rec (tolerance ~1e-3).
// mfma_i32_16x16x64_i8: per-lane 16B k-chunk -- same A/B-symmetric pattern
// as the verified bf16 kernels (internal k-permutation cancels between A
// and B; i32 accumulation exact). acc0 < 2^22, acc1 < 2^24: exact f32.
// LDS: 4-slot XOR swizzle c_phys = kgrp ^ g(row&15), g(r) = (r+(r>>2))&3;
// read-bank balance exact (each bank 8 accesses per wave b128 read).
// Staged via inverse-swizzled SOURCE address, linear LDS dest (rule 21):
// dest byte = tid*16 + i*4096 == wave-uniform base + lane*16.
// ---------------------------------------------------------------------------
__global__ __launch_bounds__(256) void gemm_i8(
    const signed char* __restrict__ Ap, const signed char* __restrict__ Bp,
    const float* __restrict__ bias, float* __restrict__ C,
    int M, int N, int K)
{
    __shared__ signed char Ash[2][128 * 64];   // 8 KiB per limb
    __shared__ signed char Bsh[2][128 * 64];

    const int tid  = threadIdx.x;
    const int lane = tid & 63;
    const int wave = tid >> 6;
    const int gx  = gridDim.x;
    const int id  = blockIdx.x + gx * blockIdx.y;
    const int bxp = (id >> 3) % gx;
    const int byp = (id & 7) + 8 * (id / (8 * gx));
    const int bm  = byp * 128;
    const int bn  = bxp * 128;
    const int wm = (wave & 1) * 64;
    const int wn = (wave >> 1) * 64;

    const int laneR = lane & 15;
    const int kgrp  = lane >> 4;
    const int gsw   = (laneR + (laneR >> 2)) & 3;
    const int slotb = ((kgrp ^ gsw) << 4);         // swizzled 16B chunk

    // staging constants: thread covers rows {srow, srow+64}, phys slot sp
    const int srow = tid >> 2;                     // 0..63
    const int sp   = tid & 3;

    intx4 acc0[4][4], acc1[4][4];
#pragma unroll
    for (int t = 0; t < 4; ++t)
#pragma unroll
        for (int u = 0; u < 4; ++u) {
            acc0[t][u] = (intx4)0;
            acc1[t][u] = (intx4)0;
        }

    for (int k0 = 0; k0 < K; k0 += 64) {
        __syncthreads();   // prior iteration's LDS reads complete
#pragma unroll
        for (int l = 0; l < 2; ++l) {
            const signed char* pa = Ap + (size_t)l * M * K + k0;
            const signed char* pb = Bp + (size_t)l * N * K + k0;
#pragma unroll
            for (int i = 0; i < 2; ++i) {
                int row = srow + i * 64;
                int rg  = row & 15;
                int c   = sp ^ ((rg + (rg >> 2)) & 3);   // inverse-swz source
                async16(pa + (size_t)(bm + row) * K + c * 16,
                        &Ash[l][row * 64 + sp * 16]);    // linear dest
                async16(pb + (size_t)(bn + row) * K + c * 16,
                        &Bsh[l][row * 64 + sp * 16]);
            }
        }
        __syncthreads();   // drains vmcnt (global_load_lds)

        intx4 a[4][2], b[4][2];
#pragma unroll
        for (int l = 0; l < 2; ++l)
#pragma unroll
            for (int m = 0; m < 4; ++m) {
                a[m][l] = *(const intx4*)&Ash[l][(wm + m * 16 + laneR) * 64 + slotb];
                b[m][l] = *(const intx4*)&Bsh[l][(wn + m * 16 + laneR) * 64 + slotb];
            }

#pragma unroll
        for (int m = 0; m < 4; ++m)
#pragma unroll
            for (int u = 0; u < 4; ++u) {
                acc0[m][u] = __builtin_amdgcn_mfma_i32_16x16x64_i8(
                    a[m][0], b[u][0], acc0[m][u], 0, 0, 0);
                acc1[m][u] = __builtin_amdgcn_mfma_i32_16x16x64_i8(
                    a[m][1], b[u][0], acc1[m][u], 0, 0, 0);
                acc1[m][u] = __builtin_amdgcn_mfma_i32_16x16x64_i8(
                    a[m][0], b[u][1], acc1[m][u], 0, 0, 0);
            }
    }

    // epilogue: D col=lane&15, row=(lane>>4)*4+reg (dtype-independent layout)
#pragma unroll
    for (int t = 0; t < 4; ++t) {
        int row0 = bm + wm + t * 16 + (lane >> 4) * 4;
#pragma unroll
        for (int u = 0; u < 4; ++u) {
            int col = bn + wn + u * 16 + (lane & 15);
            float bb = bias[col];
#pragma unroll
            for (int r = 0; r < 4; ++r) {
                float v = (float)acc0[t][u][r] * 0x1p-18f
                        + (float)acc1[t][u][r] * 0x1p-26f + bb;
                C[(size_t)(row0 + r) * N + col] = v;
            }
        }
    }
}

// ---------------------------------------------------------------------------
__global__ __launch_bounds__(64) void rownorm128(const float* __restrict__ in,
                                                 float* __restrict__ out)
{
    int row = blockIdx.x;
    int l = threadIdx.x;
    const float* p = in + (size_t)row * 128;
    float v0 = p[l], v1 = p[l + 64];
    float s = v0 * v0 + v1 * v1;
#pragma unroll
    for (int o = 32; o > 0; o >>= 1) s += __shfl_xor(s, o, 64);
    float inv = 1.0f / sqrtf(s);
    float* q = out + (size_t)row * 128;
    q[l] = v0 * inv;
    q[l + 64] = v1 * inv;
}

// ---------------------------------------------------------------------------
__global__ __launch_bounds__(128) void seg_scatter(
    const float* __restrict__ z, const int* __restrict__ ids,
    float* __restrict__ seg, float* __restrict__ freq)
{
    int row = blockIdx.x;
    int l = threadIdx.x;
    int id = ids[row];
    atomicAdd(&seg[(size_t)id * 128 + l], z[(size_t)row * 128 + l]);
    if (l == 0) atomicAdd(&freq[id], 1.0f);
}

// ---------------------------------------------------------------------------
__global__ __launch_bounds__(128) void avg_kernel(
    const float* __restrict__ seg, const float* __restrict__ freq,
    float* __restrict__ avg)
{
    int i = blockIdx.x;
    int l = threadIdx.x;
    float f = fmaxf(freq[i], 1.0f);
    avg[(size_t)i * 128 + l] = seg[(size_t)i * 128 + l] / f;
}

// ---------------------------------------------------------------------------
__global__ __launch_bounds__(128) void argmax_kernel(
    const float* __restrict__ avg, const float* __restrict__ cn,
    int* __restrict__ cids, float* __restrict__ cids_f)
{
    __shared__ float arow[128];
    __shared__ float lg[NK];
    int row = blockIdx.x;
    int t = threadIdx.x;
    arow[t] = avg[(size_t)row * 128 + t];
    __syncthreads();
    if (t < NK) {
        float d = 0.f;
        const float* c = cn + (size_t)t * 128;
#pragma unroll 8
        for (int i = 0; i < 128; ++i) d += arow[i] * c[i];
        lg[t] = d;
    }
    __syncthreads();
    if (t == 0) {
        float best = lg[0];
        int bi = 0;
        for (int k = 1; k < NK; ++k) {
            if (lg[k] > best) { best = lg[k]; bi = k; }
        }
        cids[row] = bi;
        cids_f[row] = (float)bi;
    }
}

// ---------------------------------------------------------------------------
__global__ __launch_bounds__(256) void build_masks(
    const float* __restrict__ bow, unsigned long long* __restrict__ masks,
    float* __restrict__ cnt)
{
    int j = blockIdx.x * 256 + threadIdx.x;
    if (j >= NV) return;
    unsigned long long m0 = 0, m1 = 0;
    for (int b = 0; b < 64; ++b)
        if (bow[(size_t)b * VOCAB + j] != 0.f) m0 |= 1ull << b;
    for (int b = 0; b < 64; ++b)
        if (bow[(size_t)(b + 64) * VOCAB + j] != 0.f) m1 |= 1ull << b;
    masks[2 * j] = m0;
    masks[2 * j + 1] = m1;
    cnt[j] = (float)(__popcll(m0) + __popcll(m1));
}

// ---------------------------------------------------------------------------
__global__ __launch_bounds__(256) void co_kernel(
    const unsigned long long* __restrict__ masks, const float* __restrict__ cnt,
    float* __restrict__ co)
{
    int j = blockIdx.x * 256 + threadIdx.x;
    unsigned long long m0 = masks[2 * j], m1 = masks[2 * j + 1];
    float cj = cnt[j];
    int ibase = blockIdx.y * 64;
    for (int ii = 0; ii < 64; ++ii) {
        int i = ibase + ii;
        unsigned long long a0 = masks[2 * i], a1 = masks[2 * i + 1];
        float ci = cnt[i];
        float c = (float)(__popcll(a0 & m0) + __popcll(a1 & m1));
        co[(size_t)i * NV + j] = (float)NB * c / (ci * cj);
    }
}

// ---------------------------------------------------------------------------
__global__ __launch_bounds__(128) void cluster_scan(
    const float* __restrict__ avg, const int* __restrict__ cids,
    const float* __restrict__ freq, const float* __restrict__ vw,
    const float* __restrict__ centers, const float* __restrict__ counts,
    float* __restrict__ out_centers)
{
    __shared__ int list[NV];
    __shared__ float coef[NV];
    __shared__ int tcnt[128];
    __shared__ int tot;
    __shared__ float Ptot;

    int k = blockIdx.x;
    int t = threadIdx.x;

    int base = t * (NV / 128);
    int c = 0;
    for (int s = 0; s < NV / 128; ++s) {
        int i = base + s;
        if (cids[i] == k && freq[i] > 0.f) c++;
    }
    tcnt[t] = c;
    __syncthreads();
    if (t == 0) {
        int run = 0;
        for (int x = 0; x < 128; ++x) { int v = tcnt[x]; tcnt[x] = run; run += v; }
        tot = run;
    }
    __syncthreads();
    int off = tcnt[t];
    for (int s = 0; s < NV / 128; ++s) {
        int i = base + s;
        if (cids[i] == k && freq[i] > 0.f) list[off++] = i;
    }
    __syncthreads();
    int m = tot;

    float c0 = counts[k];
    for (int j = t; j < m; j += 128)
        coef[j] = vw[list[j]] / (c0 + (float)(j + 1));
    __syncthreads();
    if (t == 0) {
        float suf = 1.f;
        for (int j = m - 1; j >= 0; --j) {
            float e = coef[j];
            coef[j] = e * suf;
            suf *= (1.f - e);
        }
        Ptot = suf;
    }
    __syncthreads();

    float accv = Ptot * centers[(size_t)k * 128 + t];
    for (int j = 0; j < m; ++j)
        accv += coef[j] * avg[(size_t)list[j] * 128 + t];
    out_centers[(size_t)k * 128 + t] = accv;
}

// ---------------------------------------------------------------------------
__global__ __launch_bounds__(64) void cn_norm(const float* __restrict__ centers,
                                              float* __restrict__ cn)
{
    int row = blockIdx.x;
    int l = threadIdx.x;
    const float* p = centers + (size_t)row * 128;
    float v0 = p[l], v1 = p[l + 64];
    float s = v0 * v0 + v1 * v1;
#pragma unroll
    for (int o = 32; o > 0; o >>= 1) s += __shfl_xor(s, o, 64);
    float inv = 1.0f / sqrtf(s);
    cn[(size_t)row * 128 + l] = v0 * inv;
    cn[(size_t)row * 128 + l + 64] = v1 * inv;
}

// ---------------------------------------------------------------------------
extern "C" void kernel_launch(void* const* d_in, const int* in_sizes, int n_in,
                              void* d_out, int out_size, void* d_ws, size_t ws_size,
                              hipStream_t stream)
{
    const int*   input_ids = (const int*)d_in[0];
    const float* token_embs = (const float*)d_in[3];
    const float* bow       = (const float*)d_in[4];
    const float* enc_w1    = (const float*)d_in[5];
    const float* enc_b1    = (const float*)d_in[6];
    const float* enc_w2    = (const float*)d_in[7];
    const float* enc_b2    = (const float*)d_in[8];
    const float* dec_w1    = (const float*)d_in[9];
    const float* dec_b1    = (const float*)d_in[10];
    const float* dec_w2    = (const float*)d_in[11];
    const float* dec_b2    = (const float*)d_in[12];
    const float* centers   = (const float*)d_in[13];
    const float* counts    = (const float*)d_in[14];
    const float* vocab_w   = (const float*)d_in[15];

    float* out = (float*)d_out;
    const size_t OFF_CO  = 0;                       // 4096*4096
    const size_t OFF_REC = 16777216;                // 32768*768
    const size_t OFF_AVG = OFF_REC + 25165824;      // 4096*128
    const size_t OFF_CID = OFF_AVG + 524288;        // 4096
    const size_t OFF_NC  = OFF_CID + 4096;          // 100*128

    // workspace layout
    float* h    = (float*)d_ws;                     // 32768*512 f32 (dec1: i8 planes)
    float* z    = h + (size_t)M_TOK * HID;          // 32768*128
    float* seg  = z + (size_t)M_TOK * LAT;          // 4096*128
    float* freq = seg + (size_t)NV * LAT;           // 4096
    float* cn   = freq + NV;                        // 100*128
    float* cntv = cn + (size_t)NK * LAT;            // 4096
    int*   cids = (int*)(cntv + NV);                // 4096
    unsigned long long* masks = (unsigned long long*)(cids + NV); // 4096*2
    unsigned short* wt1 = (unsigned short*)(masks + 2 * NV);      // 3*512*768
    unsigned short* wt2 = wt1 + (size_t)3 * HID * BERT;           // 3*128*512
    unsigned short* wt3 = wt2 + (size_t)3 * LAT * HID;            // 3*512*128
    signed char*    wi4 = (signed char*)(wt3 + (size_t)3 * HID * LAT); // 2*768*512 i8

    // zero the atomic targets
    hipMemsetAsync(seg, 0, (size_t)(NV * LAT + NV) * sizeof(float), stream);

    // weight split+transpose
    wsplit<<<(BERT * HID + 255) / 256, 256, 0, stream>>>(enc_w1, wt1, BERT, HID);
    wsplit<<<(HID * LAT + 255) / 256, 256, 0, stream>>>(enc_w2, wt2, HID, LAT);
    wsplit<<<(LAT * HID + 255) / 256, 256, 0, stream>>>(dec_w1, wt3, LAT, HID);
    wsplit_i8<<<(HID * BERT + 255) / 256, 256, 0, stream>>>(
        dec_w2, wi4, HID, BERT, 262144.f);          // scale 2^18

    // encoder (r0-exact: 3-limb, 6 products -> z/argmax path bit-identical)
    gemm_mfma<3, true ><<<dim3(HID / 128, M_TOK / 128), 256, 0, stream>>>(
        token_embs, wt1, enc_b1, h, M_TOK, HID, BERT);
    gemm_mfma<3, false><<<dim3(LAT / 128, M_TOK / 128), 256, 0, stream>>>(
        h, wt2, enc_b2, z, M_TOK, LAT, HID);
    rownorm128<<<M_TOK, 64, 0, stream>>>(z, z);

    // decoder GEMM1 (r0 math; epilogue stores h2 as i8 2-limb planes)
    gemm_mfma<2, true, 1><<<dim3(HID / 128, M_TOK / 128), 256, 0, stream>>>(
        z, wt3, dec_b1, h, M_TOK, HID, LAT);

    // decoder GEMM2: i8 fixed-point (2x MFMA rate, half the instructions)
    gemm_i8<<<dim3(BERT / 128, M_TOK / 128), 256, 0, stream>>>(
        (const signed char*)h, wi4, dec_b2, out + OFF_REC, M_TOK, BERT, HID);

    // segment mean
    seg_scatter<<<M_TOK, 128, 0, stream>>>(z, input_ids, seg, freq);
    avg_kernel<<<NV, 128, 0, stream>>>(seg, freq, out + OFF_AVG);

    // cluster assignment
    cn_norm<<<NK, 64, 0, stream>>>(centers, cn);
    argmax_kernel<<<NV, 128, 0, stream>>>(out + OFF_AVG, cn, cids, out + OFF_CID);

    // co-occurrence matrix
    build_masks<<<NV / 256, 256, 0, stream>>>(bow, masks, cntv);
    co_kernel<<<dim3(NV / 256, NV / 64), 256, 0, stream>>>(masks, cntv, out + OFF_CO);

    // online center update (closed form)
    cluster_scan<<<NK, 128, 0, stream>>>(out + OFF_AVG, cids, freq, vocab_w,
                                         centers, counts, out + OFF_NC);
}